// Round 10
// baseline (337.490 us; speedup 1.0000x reference)
//
#include <hip/hip_runtime.h>

// ---------------------------------------------------------------------------
// GCN 2-layer forward on MI355X.
// out = relu(Ahat * relu((Ahat*X)*W1 + b1) * W2 + b2),  Ahat = D^-1/2 (A+I) D^-1/2
// R1: multi-block scan. R2: agg unroll-8; 128x128 fp32 GEMM.
// R3: GEMMs -> bf16-split MFMA (Ootomo 3-mult), packed (hi<<16|lo) operands.
// R4: agg bf16 gather, wave/node, 8x256B rows in flight.
// R5-R8: XCD column-slicing falsified; kept fused edge records.
// R9: record-based agg + rec prefetch + nt stores -> 336us; fill_csr_ew now #1
//     (54us, WRITE 52.7MB for 6.4MB of records: partial-line scatter).
// R10: 4B packed records {deg:15|src:17} (halve dirtied lines; agg recomputes
//     w=rsqrt(deg+1) in-register, 2 VALU/edge under gather latency). cursor
//     un-aliased from counts (fill reads counts[src]). nt scatter stores.
//     ASSUMES max degree < 32768 (Poisson(16) here, max ~45).
// ---------------------------------------------------------------------------

#define C_IN   128
#define C_HID  256
#define C_OUT  128

typedef __attribute__((ext_vector_type(8))) short short8;
typedef __attribute__((ext_vector_type(4))) float floatx4;

__device__ __forceinline__ unsigned short f2bf(float f) {
    unsigned u = __float_as_uint(f);
    u += 0x7FFFu + ((u >> 16) & 1u);      // RNE
    return (unsigned short)(u >> 16);
}
__device__ __forceinline__ float bf2f(unsigned short b) {
    return __uint_as_float(((unsigned)b) << 16);
}
__device__ __forceinline__ unsigned pack_hilo(float f) {
    unsigned short hi = f2bf(f);
    unsigned short lo = f2bf(f - bf2f(hi));
    return ((unsigned)hi << 16) | (unsigned)lo;
}
__device__ __forceinline__ float bflo(unsigned v) {   // low short as bf16->f32
    return __uint_as_float((v & 0xFFFFu) << 16);
}
__device__ __forceinline__ float bfhi(unsigned v) {   // high short as bf16->f32
    return __uint_as_float(v & 0xFFFF0000u);
}

// ---------------- degree histogram ----------------
__global__ void deg_kernel(const int* __restrict__ dst, int* __restrict__ counts, int E) {
    int e = blockIdx.x * blockDim.x + threadIdx.x;
    if (e < E) atomicAdd(&counts[dst[e]], 1);
}

// ---------------- multi-block scan: 1024 counts per block ----------------
#define SCHUNK 1024

__global__ __launch_bounds__(256) void scan_reduce(const int* __restrict__ counts,
                                                   int* __restrict__ block_sums, int n) {
    int b = blockIdx.x;
    int base = b * SCHUNK;
    int t = threadIdx.x;
    int s = 0;
    #pragma unroll
    for (int u = 0; u < 4; ++u) {
        int i = base + t * 4 + u;
        if (i < n) s += counts[i];
    }
    #pragma unroll
    for (int off = 32; off; off >>= 1) s += __shfl_down(s, off, 64);
    __shared__ int ws[4];
    int wave = t >> 6;
    if ((t & 63) == 0) ws[wave] = s;
    __syncthreads();
    if (t == 0) block_sums[b] = ws[0] + ws[1] + ws[2] + ws[3];
}

__global__ __launch_bounds__(64) void scan_sums(const int* __restrict__ block_sums,
                                                int* __restrict__ block_base, int nb,
                                                int* __restrict__ offsets, int n, int E) {
    int t = threadIdx.x;
    int v = (t < nb) ? block_sums[t] : 0;
    int x = v;
    #pragma unroll
    for (int off = 1; off < 64; off <<= 1) {
        int y = __shfl_up(x, off, 64);
        if (t >= off) x += y;
    }
    if (t < nb) block_base[t] = x - v;
    if (t == 0) offsets[n] = E;
}

// reads counts (PRESERVED), writes offsets + cursor (separate) + fused dinv.
__global__ __launch_bounds__(256) void scan_apply(const int* __restrict__ counts,
                                                  const int* __restrict__ block_base,
                                                  int* __restrict__ offsets,
                                                  int* __restrict__ cursor,
                                                  float* __restrict__ dinv, int n) {
    int b = blockIdx.x;
    int base_i = b * SCHUNK;
    int t = threadIdx.x;
    int c[4];
    #pragma unroll
    for (int u = 0; u < 4; ++u) {
        int i = base_i + t * 4 + u;
        c[u] = (i < n) ? counts[i] : 0;
    }
    int tot = c[0] + c[1] + c[2] + c[3];
    int x = tot;
    int lane = t & 63;
    #pragma unroll
    for (int off = 1; off < 64; off <<= 1) {
        int y = __shfl_up(x, off, 64);
        if (lane >= off) x += y;
    }
    __shared__ int ws[4];
    int wave = t >> 6;
    if (lane == 63) ws[wave] = x;
    __syncthreads();
    int wbase = 0;
    for (int w = 0; w < wave; ++w) wbase += ws[w];
    int run = block_base[b] + wbase + (x - tot);
    #pragma unroll
    for (int u = 0; u < 4; ++u) {
        int i = base_i + t * 4 + u;
        if (i < n) {
            offsets[i] = run;
            cursor[i]  = run;
            dinv[i]    = rsqrtf((float)(c[u] + 1));   // +1 self-loop
            run += c[u];
        }
    }
}

// fill CSR with 4B packed records {deg[src]:15 | src:17}
__global__ void fill_csr_pk(const int* __restrict__ src, const int* __restrict__ dst,
                            const int* __restrict__ counts, int* __restrict__ cursor,
                            unsigned* __restrict__ csr_pk, int E) {
    int e = blockIdx.x * blockDim.x + threadIdx.x;
    if (e < E) {
        int s = src[e];
        int degs = counts[s];                       // assumed < 32768
        int p = atomicAdd(&cursor[dst[e]], 1);
        unsigned rec = (unsigned)s | ((unsigned)degs << 17);
        __builtin_nontemporal_store(rec, &csr_pk[p]);
    }
}

// ---------------- weight cast+transpose: W[K][N] f32 -> Wt[N][K] packed ----
__global__ void cast_w_t(const float* __restrict__ W, unsigned* __restrict__ Wtp,
                         int K, int N) {
    int idx = blockIdx.x * blockDim.x + threadIdx.x;
    if (idx < K * N) {
        int k = idx / N, nn = idx - k * N;
        Wtp[(size_t)nn * K + k] = pack_hilo(W[idx]);
    }
}

// ---------------- x -> bf16 cast, 4 elems/thread ----------------
__global__ void cast_x_bf16(const float* __restrict__ x, unsigned* __restrict__ xb2,
                            int count4) {
    int idx = blockIdx.x * blockDim.x + threadIdx.x;
    if (idx < count4) {
        float4 f = ((const float4*)x)[idx];
        unsigned lo = (unsigned)f2bf(f.x) | ((unsigned)f2bf(f.y) << 16);
        unsigned hi = (unsigned)f2bf(f.z) | ((unsigned)f2bf(f.w) << 16);
        ((uint2*)xb2)[idx] = make_uint2(lo, hi);
    }
}

// ---------------- pull aggregation (R10): wave/node, packed records ---------
// Wave = node; lane covers 2 cols (one uint of the 256B bf16 row -> each edge
// gather is one 256B wave txn). Batch of 8 edges in flight; next batch's
// records prefetched (nt). Weight recomputed as rsqrt(deg+1) from the packed
// record (2 VALU/edge, hidden under gather latency). Output stored nt.
// csr_pk has >=16 recs slack past E.
__global__ __launch_bounds__(256) void agg_kernel(
        const unsigned short* __restrict__ hb, const int* __restrict__ offsets,
        const unsigned* __restrict__ csr_pk, const float* __restrict__ dinv,
        const float* __restrict__ bias, float* __restrict__ out_f,
        unsigned* __restrict__ out_p, int relu_flag, int n) {
    int node = blockIdx.x * 4 + (threadIdx.x >> 6);
    if (node >= n) return;
    int lane = threadIdx.x & 63;

    const unsigned* hrow = (const unsigned*)hb;   // row j = 64 uints
    float di = dinv[node];
    unsigned sv = hrow[(size_t)node * 64 + lane];
    float a0 = di * bflo(sv);
    float a1 = di * bfhi(sv);

    int lo = offsets[node], hi = offsets[node + 1];

    unsigned rec[8];
    #pragma unroll
    for (int u = 0; u < 8; ++u)
        rec[u] = __builtin_nontemporal_load(&csr_pk[lo + u]);   // slack covers deg==0

    for (int k = lo; k < hi; k += 8) {
        int jj[8]; float w[8];
        #pragma unroll
        for (int u = 0; u < 8; ++u) {
            bool ok = (k + u) < hi;
            jj[u] = ok ? (int)(rec[u] & 0x1FFFFu) : 0;
            w[u]  = ok ? rsqrtf((float)((rec[u] >> 17) + 1u)) : 0.0f;
        }
        unsigned v[8];
        #pragma unroll
        for (int u = 0; u < 8; ++u)
            v[u] = hrow[(size_t)jj[u] * 64 + lane];
        #pragma unroll
        for (int u = 0; u < 8; ++u)                             // prefetch next batch
            rec[u] = __builtin_nontemporal_load(&csr_pk[k + 8 + u]);
        #pragma unroll
        for (int u = 0; u < 8; ++u) {
            a0 += w[u] * bflo(v[u]);
            a1 += w[u] * bfhi(v[u]);
        }
    }

    int c0 = lane * 2;
    float v0 = di * a0, v1f = di * a1;
    if (bias) { v0 += bias[c0]; v1f += bias[c0 + 1]; }
    if (relu_flag) { v0 = fmaxf(v0, 0.0f); v1f = fmaxf(v1f, 0.0f); }
    if (out_f) {
        unsigned long long ov = ((unsigned long long)__float_as_uint(v1f) << 32)
                              | (unsigned long long)__float_as_uint(v0);
        __builtin_nontemporal_store(ov, (unsigned long long*)(out_f + (size_t)node * 128 + c0));
    } else {
        unsigned long long ov = ((unsigned long long)pack_hilo(v1f) << 32)
                              | (unsigned long long)pack_hilo(v0);
        __builtin_nontemporal_store(ov, (unsigned long long*)(out_p + (size_t)node * 128 + c0));
    }
}

// ---------------- bf16-split MFMA GEMM, 128x128 tile ----------------------
// C = A*B (+bias)(relu). A: [M][K] packed hi|lo. Btp: [N][K] packed (B^T).
// Output: Cf (f32) | Cp (packed) | Cb (bf16).
#define TM 128
#define TN 128
#define TK 32
#define LDK 40    // halfs per LDS row: 80B stride -> b128 frag reads 2-way (free)

__global__ __launch_bounds__(256) void mfma_gemm(
        const unsigned* __restrict__ Ap, const unsigned* __restrict__ Btp,
        const float* __restrict__ bias, float* __restrict__ Cf,
        unsigned* __restrict__ Cp, unsigned short* __restrict__ Cb,
        int M, int K, int N, int relu_flag) {
    __shared__ unsigned short smem[4 * 128 * LDK];   // 40 KB
    unsigned short* As_hi = smem;
    unsigned short* As_lo = smem + 128 * LDK;
    unsigned short* Bs_hi = smem + 2 * 128 * LDK;
    unsigned short* Bs_lo = smem + 3 * 128 * LDK;

    int tid = threadIdx.x;
    int lane = tid & 63;
    int wv = tid >> 6;
    int m0w = (wv & 1) * 64;
    int n0w = (wv >> 1) * 64;
    int row0 = blockIdx.x * TM;
    int col0 = blockIdx.y * TN;

    int sr  = tid >> 2;            // 0..63 (staging row)
    int skc = (tid & 3) * 8;       // packed-uint offset within 32-k

    floatx4 acc[4][4];
    #pragma unroll
    for (int i = 0; i < 4; ++i)
        #pragma unroll
        for (int j = 0; j < 4; ++j)
            acc[i][j] = (floatx4){0.f, 0.f, 0.f, 0.f};

    for (int k0 = 0; k0 < K; k0 += TK) {
        uint4 av[2][2], bv[2][2];
        #pragma unroll
        for (int p = 0; p < 2; ++p) {
            int r = sr + p * 64;
            int ar = row0 + r;
            if (ar < M) {
                const uint4* pa = (const uint4*)(Ap + (size_t)ar * K + k0 + skc);
                av[p][0] = pa[0];  av[p][1] = pa[1];
            } else {
                av[p][0] = make_uint4(0, 0, 0, 0);
                av[p][1] = make_uint4(0, 0, 0, 0);
            }
            const uint4* pb = (const uint4*)(Btp + (size_t)(col0 + r) * K + k0 + skc);
            bv[p][0] = pb[0];  bv[p][1] = pb[1];
        }
        __syncthreads();          // prev iter frag reads done
        #pragma unroll
        for (int p = 0; p < 2; ++p) {
            int r = sr + p * 64;
            unsigned ua[8] = {av[p][0].x, av[p][0].y, av[p][0].z, av[p][0].w,
                              av[p][1].x, av[p][1].y, av[p][1].z, av[p][1].w};
            unsigned ub[8] = {bv[p][0].x, bv[p][0].y, bv[p][0].z, bv[p][0].w,
                              bv[p][1].x, bv[p][1].y, bv[p][1].z, bv[p][1].w};
            short8 ahs, als, bhs, bls;
            #pragma unroll
            for (int j = 0; j < 8; ++j) {
                ahs[j] = (short)(ua[j] >> 16);  als[j] = (short)(ua[j] & 0xFFFFu);
                bhs[j] = (short)(ub[j] >> 16);  bls[j] = (short)(ub[j] & 0xFFFFu);
            }
            *(short8*)&As_hi[r * LDK + skc] = ahs;
            *(short8*)&As_lo[r * LDK + skc] = als;
            *(short8*)&Bs_hi[r * LDK + skc] = bhs;
            *(short8*)&Bs_lo[r * LDK + skc] = bls;
        }
        __syncthreads();
        short8 ah[4], al[4], bh[4], bl[4];
        int ka = (lane >> 4) * 8;
        #pragma unroll
        for (int mi = 0; mi < 4; ++mi) {
            int rr = m0w + mi * 16 + (lane & 15);
            ah[mi] = *(const short8*)&As_hi[rr * LDK + ka];
            al[mi] = *(const short8*)&As_lo[rr * LDK + ka];
        }
        #pragma unroll
        for (int ni = 0; ni < 4; ++ni) {
            int cc = n0w + ni * 16 + (lane & 15);
            bh[ni] = *(const short8*)&Bs_hi[cc * LDK + ka];
            bl[ni] = *(const short8*)&Bs_lo[cc * LDK + ka];
        }
        #pragma unroll
        for (int mi = 0; mi < 4; ++mi)
            #pragma unroll
            for (int ni = 0; ni < 4; ++ni) {
                acc[mi][ni] = __builtin_amdgcn_mfma_f32_16x16x32_bf16(al[mi], bh[ni], acc[mi][ni], 0, 0, 0);
                acc[mi][ni] = __builtin_amdgcn_mfma_f32_16x16x32_bf16(ah[mi], bl[ni], acc[mi][ni], 0, 0, 0);
                acc[mi][ni] = __builtin_amdgcn_mfma_f32_16x16x32_bf16(ah[mi], bh[ni], acc[mi][ni], 0, 0, 0);
            }
    }

    // epilogue: C/D mapping col=lane&15, row=(lane>>4)*4+reg
    #pragma unroll
    for (int mi = 0; mi < 4; ++mi) {
        #pragma unroll
        for (int reg = 0; reg < 4; ++reg) {
            int r = row0 + m0w + mi * 16 + (lane >> 4) * 4 + reg;
            if (r < M) {
                #pragma unroll
                for (int ni = 0; ni < 4; ++ni) {
                    int c = col0 + n0w + ni * 16 + (lane & 15);
                    float v = acc[mi][ni][reg];
                    if (bias) v += bias[c];
                    if (relu_flag) v = fmaxf(v, 0.0f);
                    if (Cf)      Cf[(size_t)r * N + c] = v;
                    else if (Cp) Cp[(size_t)r * N + c] = pack_hilo(v);
                    else         Cb[(size_t)r * N + c] = f2bf(v);
                }
            }
        }
    }
}

// ---------------------------------------------------------------------------
extern "C" void kernel_launch(void* const* d_in, const int* in_sizes, int n_in,
                              void* d_out, int out_size, void* d_ws, size_t ws_size,
                              hipStream_t stream) {
    const float* x  = (const float*)d_in[0];
    const int*   ei = (const int*)d_in[1];
    const float* W1 = (const float*)d_in[2];
    const float* b1 = (const float*)d_in[3];
    const float* W2 = (const float*)d_in[4];
    const float* b2 = (const float*)d_in[5];

    const int n = in_sizes[0] / C_IN;          // 50000
    const int E = in_sizes[1] / 2;             // 800000

    const int* src = ei;
    const int* dst = ei + E;

    // workspace layout (~81 MB)
    unsigned short* h2b = (unsigned short*)d_ws;         // n*128 bf16
    unsigned* z1p = (unsigned*)(h2b + (size_t)n * C_OUT);// n*256 packed
    unsigned short* xb = (unsigned short*)(z1p + (size_t)n * C_HID); // n*128 bf16
    unsigned* w1t = (unsigned*)(xb + (size_t)n * C_IN);  // 128*256
    unsigned* w2t = w1t + C_IN * C_HID;                  // 256*128
    float*    dinv = (float*)(w2t + C_HID * C_OUT);      // n
    int* counts  = (int*)(dinv + n);                     // n (preserved)
    int* cursor  = counts + n;                           // n (separate, R10)
    int* offsets = cursor + n;                           // n+1
    unsigned* csr_pk = (unsigned*)(offsets + n + 1);     // E uint (+64 slack)
    int* block_sums = (int*)(csr_pk + E + 64);           // 64
    int* block_base = block_sums + 64;                   // 64

    unsigned* agg0p = (unsigned*)d_out;    // n*128 packed, overwritten by final out
    float*    outp  = (float*)d_out;

    const int nb = (n + SCHUNK - 1) / SCHUNK;            // 49

    // ---- CSR build ----
    hipMemsetAsync(counts, 0, (size_t)n * sizeof(int), stream);
    deg_kernel<<<(E + 255) / 256, 256, 0, stream>>>(dst, counts, E);
    scan_reduce<<<nb, 256, 0, stream>>>(counts, block_sums, n);
    scan_sums<<<1, 64, 0, stream>>>(block_sums, block_base, nb, offsets, n, E);
    scan_apply<<<nb, 256, 0, stream>>>(counts, block_base, offsets, cursor, dinv, n);
    fill_csr_pk<<<(E + 255) / 256, 256, 0, stream>>>(src, dst, counts, cursor, csr_pk, E);

    // ---- casts (tiny) ----
    cast_w_t<<<(C_IN * C_HID + 255) / 256, 256, 0, stream>>>(W1, w1t, C_IN, C_HID);
    cast_w_t<<<(C_HID * C_OUT + 255) / 256, 256, 0, stream>>>(W2, w2t, C_HID, C_OUT);
    {
        int count4 = n * C_IN / 4;
        cast_x_bf16<<<(count4 + 255) / 256, 256, 0, stream>>>(x, (unsigned*)xb, count4);
    }

    const int agg_blocks = (n + 3) / 4;

    // ---- layer 1: agg0 = Ahat*X (packed) ; z1 = relu(agg0@W1 + b1) (packed) ----
    agg_kernel<<<agg_blocks, 256, 0, stream>>>(xb, offsets, csr_pk,
                                               dinv, nullptr, nullptr, agg0p, 0, n);
    {
        dim3 grid((n + TM - 1) / TM, C_HID / TN);        // (391, 2)
        mfma_gemm<<<grid, 256, 0, stream>>>(agg0p, w1t, b1, nullptr, z1p, nullptr,
                                            n, C_IN, C_HID, 1);
    }

    // ---- layer 2: h2 = z1@W2 (bf16) ; out = relu(Ahat*h2 + b2) ----
    {
        dim3 grid((n + TM - 1) / TM, C_OUT / TN);        // (391, 1)
        mfma_gemm<<<grid, 256, 0, stream>>>(z1p, w2t, nullptr, nullptr, nullptr, h2b,
                                            n, C_HID, C_OUT, 0);
    }
    agg_kernel<<<agg_blocks, 256, 0, stream>>>(h2b, offsets, csr_pk,
                                               dinv, b2, outp, nullptr, 1, n);
}

// Round 11
// 316.852 us; speedup vs baseline: 1.0651x; 1.0651x over previous
//
#include <hip/hip_runtime.h>

// ---------------------------------------------------------------------------
// GCN 2-layer forward on MI355X.
// out = relu(Ahat * relu((Ahat*X)*W1 + b1) * W2 + b2),  Ahat = D^-1/2 (A+I) D^-1/2
// R3: GEMMs = bf16-split MFMA (Ootomo 3-mult). R9: record-based agg (best).
// R10 falsified "smaller records" for fill: random scatter dirties one 64B
//     line per record regardless of size (WRITE==E*64B); nt store made it
//     worse. Binder = cross-XCD false sharing on scattered lines.
// R11: XCD-partitioned fill. Node range claimed by blockIdx&7 (~physical XCD
//     under round-robin dispatch). Each group scans all of dst (LLC-resident),
//     keeps 1/8 -> cursor+CSR slices single-XCD: local atomics, lines fill in
//     L2 -> full-line writebacks. Normal stores. Correctness is mapping-
//     independent; only locality rides the heuristic.
// ---------------------------------------------------------------------------

#define C_IN   128
#define C_HID  256
#define C_OUT  128

typedef __attribute__((ext_vector_type(8))) short short8;
typedef __attribute__((ext_vector_type(4))) float floatx4;

__device__ __forceinline__ unsigned short f2bf(float f) {
    unsigned u = __float_as_uint(f);
    u += 0x7FFFu + ((u >> 16) & 1u);      // RNE
    return (unsigned short)(u >> 16);
}
__device__ __forceinline__ float bf2f(unsigned short b) {
    return __uint_as_float(((unsigned)b) << 16);
}
__device__ __forceinline__ unsigned pack_hilo(float f) {
    unsigned short hi = f2bf(f);
    unsigned short lo = f2bf(f - bf2f(hi));
    return ((unsigned)hi << 16) | (unsigned)lo;
}
__device__ __forceinline__ float bflo(unsigned v) {   // low short as bf16->f32
    return __uint_as_float((v & 0xFFFFu) << 16);
}
__device__ __forceinline__ float bfhi(unsigned v) {   // high short as bf16->f32
    return __uint_as_float(v & 0xFFFF0000u);
}

// ---------------- degree histogram ----------------
__global__ void deg_kernel(const int* __restrict__ dst, int* __restrict__ counts, int E) {
    int e = blockIdx.x * blockDim.x + threadIdx.x;
    if (e < E) atomicAdd(&counts[dst[e]], 1);
}

// ---------------- multi-block scan: 1024 counts per block ----------------
#define SCHUNK 1024

__global__ __launch_bounds__(256) void scan_reduce(const int* __restrict__ counts,
                                                   int* __restrict__ block_sums, int n) {
    int b = blockIdx.x;
    int base = b * SCHUNK;
    int t = threadIdx.x;
    int s = 0;
    #pragma unroll
    for (int u = 0; u < 4; ++u) {
        int i = base + t * 4 + u;
        if (i < n) s += counts[i];
    }
    #pragma unroll
    for (int off = 32; off; off >>= 1) s += __shfl_down(s, off, 64);
    __shared__ int ws[4];
    int wave = t >> 6;
    if ((t & 63) == 0) ws[wave] = s;
    __syncthreads();
    if (t == 0) block_sums[b] = ws[0] + ws[1] + ws[2] + ws[3];
}

__global__ __launch_bounds__(64) void scan_sums(const int* __restrict__ block_sums,
                                                int* __restrict__ block_base, int nb,
                                                int* __restrict__ offsets, int n, int E) {
    int t = threadIdx.x;
    int v = (t < nb) ? block_sums[t] : 0;
    int x = v;
    #pragma unroll
    for (int off = 1; off < 64; off <<= 1) {
        int y = __shfl_up(x, off, 64);
        if (t >= off) x += y;
    }
    if (t < nb) block_base[t] = x - v;
    if (t == 0) offsets[n] = E;
}

// reads counts (PRESERVED), writes offsets + cursor (separate) + fused dinv.
__global__ __launch_bounds__(256) void scan_apply(const int* __restrict__ counts,
                                                  const int* __restrict__ block_base,
                                                  int* __restrict__ offsets,
                                                  int* __restrict__ cursor,
                                                  float* __restrict__ dinv, int n) {
    int b = blockIdx.x;
    int base_i = b * SCHUNK;
    int t = threadIdx.x;
    int c[4];
    #pragma unroll
    for (int u = 0; u < 4; ++u) {
        int i = base_i + t * 4 + u;
        c[u] = (i < n) ? counts[i] : 0;
    }
    int tot = c[0] + c[1] + c[2] + c[3];
    int x = tot;
    int lane = t & 63;
    #pragma unroll
    for (int off = 1; off < 64; off <<= 1) {
        int y = __shfl_up(x, off, 64);
        if (lane >= off) x += y;
    }
    __shared__ int ws[4];
    int wave = t >> 6;
    if (lane == 63) ws[wave] = x;
    __syncthreads();
    int wbase = 0;
    for (int w = 0; w < wave; ++w) wbase += ws[w];
    int run = block_base[b] + wbase + (x - tot);
    #pragma unroll
    for (int u = 0; u < 4; ++u) {
        int i = base_i + t * 4 + u;
        if (i < n) {
            offsets[i] = run;
            cursor[i]  = run;
            dinv[i]    = rsqrtf((float)(c[u] + 1));   // +1 self-loop
            run += c[u];
        }
    }
}

// ---------------- XCD-partitioned CSR fill (R11) ----------------
// Group g = blockIdx&7 claims node range [g*chunk, (g+1)*chunk); scans the
// whole dst array (strided coalesced; LLC-resident after first pass), keeps
// 1/8 of edges. Its cursor + csr slices are written by this group only ->
// XCD-local atomics, full-line L2 writebacks (if blockIdx%8 ~ XCD).
// Record: {deg[src]:15 | src:17}. Normal stores (R10's nt falsified).
__global__ __launch_bounds__(256) void fill_csr_part(
        const int* __restrict__ src, const int* __restrict__ dst,
        const int* __restrict__ counts, int* __restrict__ cursor,
        unsigned* __restrict__ csr_pk, int E, int n) {
    int group = blockIdx.x & 7;
    int sub   = blockIdx.x >> 3;
    int nblk  = gridDim.x >> 3;            // blocks per group
    int chunk = (n + 7) / 8;
    int nlo = group * chunk;
    int nhi = min(n, nlo + chunk);
    int stride = nblk * 256;
    for (int e = sub * 256 + threadIdx.x; e < E; e += stride) {
        int d = dst[e];
        if (d >= nlo && d < nhi) {
            int s = src[e];
            unsigned rec = (unsigned)s | ((unsigned)counts[s] << 17);
            int p = atomicAdd(&cursor[d], 1);
            csr_pk[p] = rec;
        }
    }
}

// ---------------- weight cast+transpose: W[K][N] f32 -> Wt[N][K] packed ----
__global__ void cast_w_t(const float* __restrict__ W, unsigned* __restrict__ Wtp,
                         int K, int N) {
    int idx = blockIdx.x * blockDim.x + threadIdx.x;
    if (idx < K * N) {
        int k = idx / N, nn = idx - k * N;
        Wtp[(size_t)nn * K + k] = pack_hilo(W[idx]);
    }
}

// ---------------- x -> bf16 cast, 4 elems/thread ----------------
__global__ void cast_x_bf16(const float* __restrict__ x, unsigned* __restrict__ xb2,
                            int count4) {
    int idx = blockIdx.x * blockDim.x + threadIdx.x;
    if (idx < count4) {
        float4 f = ((const float4*)x)[idx];
        unsigned lo = (unsigned)f2bf(f.x) | ((unsigned)f2bf(f.y) << 16);
        unsigned hi = (unsigned)f2bf(f.z) | ((unsigned)f2bf(f.w) << 16);
        ((uint2*)xb2)[idx] = make_uint2(lo, hi);
    }
}

// ---------------- pull aggregation: wave/node, packed records (R9/R10) -----
// Wave = node; lane covers 2 cols (one uint of the 256B bf16 row). Batch of 8
// edges in flight; next batch's records prefetched (nt). Weight recomputed as
// rsqrt(deg+1) (2 VALU/edge under gather latency). Output stored nt.
// csr_pk has >=16 recs slack past E.
__global__ __launch_bounds__(256) void agg_kernel(
        const unsigned short* __restrict__ hb, const int* __restrict__ offsets,
        const unsigned* __restrict__ csr_pk, const float* __restrict__ dinv,
        const float* __restrict__ bias, float* __restrict__ out_f,
        unsigned* __restrict__ out_p, int relu_flag, int n) {
    int node = blockIdx.x * 4 + (threadIdx.x >> 6);
    if (node >= n) return;
    int lane = threadIdx.x & 63;

    const unsigned* hrow = (const unsigned*)hb;   // row j = 64 uints
    float di = dinv[node];
    unsigned sv = hrow[(size_t)node * 64 + lane];
    float a0 = di * bflo(sv);
    float a1 = di * bfhi(sv);

    int lo = offsets[node], hi = offsets[node + 1];

    unsigned rec[8];
    #pragma unroll
    for (int u = 0; u < 8; ++u)
        rec[u] = __builtin_nontemporal_load(&csr_pk[lo + u]);   // slack covers deg==0

    for (int k = lo; k < hi; k += 8) {
        int jj[8]; float w[8];
        #pragma unroll
        for (int u = 0; u < 8; ++u) {
            bool ok = (k + u) < hi;
            jj[u] = ok ? (int)(rec[u] & 0x1FFFFu) : 0;
            w[u]  = ok ? rsqrtf((float)((rec[u] >> 17) + 1u)) : 0.0f;
        }
        unsigned v[8];
        #pragma unroll
        for (int u = 0; u < 8; ++u)
            v[u] = hrow[(size_t)jj[u] * 64 + lane];
        #pragma unroll
        for (int u = 0; u < 8; ++u)                             // prefetch next batch
            rec[u] = __builtin_nontemporal_load(&csr_pk[k + 8 + u]);
        #pragma unroll
        for (int u = 0; u < 8; ++u) {
            a0 += w[u] * bflo(v[u]);
            a1 += w[u] * bfhi(v[u]);
        }
    }

    int c0 = lane * 2;
    float v0 = di * a0, v1f = di * a1;
    if (bias) { v0 += bias[c0]; v1f += bias[c0 + 1]; }
    if (relu_flag) { v0 = fmaxf(v0, 0.0f); v1f = fmaxf(v1f, 0.0f); }
    if (out_f) {
        unsigned long long ov = ((unsigned long long)__float_as_uint(v1f) << 32)
                              | (unsigned long long)__float_as_uint(v0);
        __builtin_nontemporal_store(ov, (unsigned long long*)(out_f + (size_t)node * 128 + c0));
    } else {
        unsigned long long ov = ((unsigned long long)pack_hilo(v1f) << 32)
                              | (unsigned long long)pack_hilo(v0);
        __builtin_nontemporal_store(ov, (unsigned long long*)(out_p + (size_t)node * 128 + c0));
    }
}

// ---------------- bf16-split MFMA GEMM, 128x128 tile ----------------------
// C = A*B (+bias)(relu). A: [M][K] packed hi|lo. Btp: [N][K] packed (B^T).
// Output: Cf (f32) | Cp (packed) | Cb (bf16).
#define TM 128
#define TN 128
#define TK 32
#define LDK 40    // halfs per LDS row: 80B stride -> b128 frag reads 2-way (free)

__global__ __launch_bounds__(256) void mfma_gemm(
        const unsigned* __restrict__ Ap, const unsigned* __restrict__ Btp,
        const float* __restrict__ bias, float* __restrict__ Cf,
        unsigned* __restrict__ Cp, unsigned short* __restrict__ Cb,
        int M, int K, int N, int relu_flag) {
    __shared__ unsigned short smem[4 * 128 * LDK];   // 40 KB
    unsigned short* As_hi = smem;
    unsigned short* As_lo = smem + 128 * LDK;
    unsigned short* Bs_hi = smem + 2 * 128 * LDK;
    unsigned short* Bs_lo = smem + 3 * 128 * LDK;

    int tid = threadIdx.x;
    int lane = tid & 63;
    int wv = tid >> 6;
    int m0w = (wv & 1) * 64;
    int n0w = (wv >> 1) * 64;
    int row0 = blockIdx.x * TM;
    int col0 = blockIdx.y * TN;

    int sr  = tid >> 2;            // 0..63 (staging row)
    int skc = (tid & 3) * 8;       // packed-uint offset within 32-k

    floatx4 acc[4][4];
    #pragma unroll
    for (int i = 0; i < 4; ++i)
        #pragma unroll
        for (int j = 0; j < 4; ++j)
            acc[i][j] = (floatx4){0.f, 0.f, 0.f, 0.f};

    for (int k0 = 0; k0 < K; k0 += TK) {
        uint4 av[2][2], bv[2][2];
        #pragma unroll
        for (int p = 0; p < 2; ++p) {
            int r = sr + p * 64;
            int ar = row0 + r;
            if (ar < M) {
                const uint4* pa = (const uint4*)(Ap + (size_t)ar * K + k0 + skc);
                av[p][0] = pa[0];  av[p][1] = pa[1];
            } else {
                av[p][0] = make_uint4(0, 0, 0, 0);
                av[p][1] = make_uint4(0, 0, 0, 0);
            }
            const uint4* pb = (const uint4*)(Btp + (size_t)(col0 + r) * K + k0 + skc);
            bv[p][0] = pb[0];  bv[p][1] = pb[1];
        }
        __syncthreads();          // prev iter frag reads done
        #pragma unroll
        for (int p = 0; p < 2; ++p) {
            int r = sr + p * 64;
            unsigned ua[8] = {av[p][0].x, av[p][0].y, av[p][0].z, av[p][0].w,
                              av[p][1].x, av[p][1].y, av[p][1].z, av[p][1].w};
            unsigned ub[8] = {bv[p][0].x, bv[p][0].y, bv[p][0].z, bv[p][0].w,
                              bv[p][1].x, bv[p][1].y, bv[p][1].z, bv[p][1].w};
            short8 ahs, als, bhs, bls;
            #pragma unroll
            for (int j = 0; j < 8; ++j) {
                ahs[j] = (short)(ua[j] >> 16);  als[j] = (short)(ua[j] & 0xFFFFu);
                bhs[j] = (short)(ub[j] >> 16);  bls[j] = (short)(ub[j] & 0xFFFFu);
            }
            *(short8*)&As_hi[r * LDK + skc] = ahs;
            *(short8*)&As_lo[r * LDK + skc] = als;
            *(short8*)&Bs_hi[r * LDK + skc] = bhs;
            *(short8*)&Bs_lo[r * LDK + skc] = bls;
        }
        __syncthreads();
        short8 ah[4], al[4], bh[4], bl[4];
        int ka = (lane >> 4) * 8;
        #pragma unroll
        for (int mi = 0; mi < 4; ++mi) {
            int rr = m0w + mi * 16 + (lane & 15);
            ah[mi] = *(const short8*)&As_hi[rr * LDK + ka];
            al[mi] = *(const short8*)&As_lo[rr * LDK + ka];
        }
        #pragma unroll
        for (int ni = 0; ni < 4; ++ni) {
            int cc = n0w + ni * 16 + (lane & 15);
            bh[ni] = *(const short8*)&Bs_hi[cc * LDK + ka];
            bl[ni] = *(const short8*)&Bs_lo[cc * LDK + ka];
        }
        #pragma unroll
        for (int mi = 0; mi < 4; ++mi)
            #pragma unroll
            for (int ni = 0; ni < 4; ++ni) {
                acc[mi][ni] = __builtin_amdgcn_mfma_f32_16x16x32_bf16(al[mi], bh[ni], acc[mi][ni], 0, 0, 0);
                acc[mi][ni] = __builtin_amdgcn_mfma_f32_16x16x32_bf16(ah[mi], bl[ni], acc[mi][ni], 0, 0, 0);
                acc[mi][ni] = __builtin_amdgcn_mfma_f32_16x16x32_bf16(ah[mi], bh[ni], acc[mi][ni], 0, 0, 0);
            }
    }

    // epilogue: C/D mapping col=lane&15, row=(lane>>4)*4+reg
    #pragma unroll
    for (int mi = 0; mi < 4; ++mi) {
        #pragma unroll
        for (int reg = 0; reg < 4; ++reg) {
            int r = row0 + m0w + mi * 16 + (lane >> 4) * 4 + reg;
            if (r < M) {
                #pragma unroll
                for (int ni = 0; ni < 4; ++ni) {
                    int c = col0 + n0w + ni * 16 + (lane & 15);
                    float v = acc[mi][ni][reg];
                    if (bias) v += bias[c];
                    if (relu_flag) v = fmaxf(v, 0.0f);
                    if (Cf)      Cf[(size_t)r * N + c] = v;
                    else if (Cp) Cp[(size_t)r * N + c] = pack_hilo(v);
                    else         Cb[(size_t)r * N + c] = f2bf(v);
                }
            }
        }
    }
}

// ---------------------------------------------------------------------------
extern "C" void kernel_launch(void* const* d_in, const int* in_sizes, int n_in,
                              void* d_out, int out_size, void* d_ws, size_t ws_size,
                              hipStream_t stream) {
    const float* x  = (const float*)d_in[0];
    const int*   ei = (const int*)d_in[1];
    const float* W1 = (const float*)d_in[2];
    const float* b1 = (const float*)d_in[3];
    const float* W2 = (const float*)d_in[4];
    const float* b2 = (const float*)d_in[5];

    const int n = in_sizes[0] / C_IN;          // 50000
    const int E = in_sizes[1] / 2;             // 800000

    const int* src = ei;
    const int* dst = ei + E;

    // workspace layout (~81 MB)
    unsigned short* h2b = (unsigned short*)d_ws;         // n*128 bf16
    unsigned* z1p = (unsigned*)(h2b + (size_t)n * C_OUT);// n*256 packed
    unsigned short* xb = (unsigned short*)(z1p + (size_t)n * C_HID); // n*128 bf16
    unsigned* w1t = (unsigned*)(xb + (size_t)n * C_IN);  // 128*256
    unsigned* w2t = w1t + C_IN * C_HID;                  // 256*128
    float*    dinv = (float*)(w2t + C_HID * C_OUT);      // n
    int* counts  = (int*)(dinv + n);                     // n (preserved)
    int* cursor  = counts + n;                           // n (separate)
    int* offsets = cursor + n;                           // n+1
    unsigned* csr_pk = (unsigned*)(offsets + n + 1);     // E uint (+64 slack)
    int* block_sums = (int*)(csr_pk + E + 64);           // 64
    int* block_base = block_sums + 64;                   // 64

    unsigned* agg0p = (unsigned*)d_out;    // n*128 packed, overwritten by final out
    float*    outp  = (float*)d_out;

    const int nb = (n + SCHUNK - 1) / SCHUNK;            // 49

    // ---- CSR build ----
    hipMemsetAsync(counts, 0, (size_t)n * sizeof(int), stream);
    deg_kernel<<<(E + 255) / 256, 256, 0, stream>>>(dst, counts, E);
    scan_reduce<<<nb, 256, 0, stream>>>(counts, block_sums, n);
    scan_sums<<<1, 64, 0, stream>>>(block_sums, block_base, nb, offsets, n, E);
    scan_apply<<<nb, 256, 0, stream>>>(counts, block_base, offsets, cursor, dinv, n);
    fill_csr_part<<<8 * 391, 256, 0, stream>>>(src, dst, counts, cursor, csr_pk, E, n);

    // ---- casts (tiny) ----
    cast_w_t<<<(C_IN * C_HID + 255) / 256, 256, 0, stream>>>(W1, w1t, C_IN, C_HID);
    cast_w_t<<<(C_HID * C_OUT + 255) / 256, 256, 0, stream>>>(W2, w2t, C_HID, C_OUT);
    {
        int count4 = n * C_IN / 4;
        cast_x_bf16<<<(count4 + 255) / 256, 256, 0, stream>>>(x, (unsigned*)xb, count4);
    }

    const int agg_blocks = (n + 3) / 4;

    // ---- layer 1: agg0 = Ahat*X (packed) ; z1 = relu(agg0@W1 + b1) (packed) ----
    agg_kernel<<<agg_blocks, 256, 0, stream>>>(xb, offsets, csr_pk,
                                               dinv, nullptr, nullptr, agg0p, 0, n);
    {
        dim3 grid((n + TM - 1) / TM, C_HID / TN);        // (391, 2)
        mfma_gemm<<<grid, 256, 0, stream>>>(agg0p, w1t, b1, nullptr, z1p, nullptr,
                                            n, C_IN, C_HID, 1);
    }

    // ---- layer 2: h2 = z1@W2 (bf16) ; out = relu(Ahat*h2 + b2) ----
    {
        dim3 grid((n + TM - 1) / TM, C_OUT / TN);        // (391, 1)
        mfma_gemm<<<grid, 256, 0, stream>>>(z1p, w2t, nullptr, nullptr, nullptr, h2b,
                                            n, C_HID, C_OUT, 0);
    }
    agg_kernel<<<agg_blocks, 256, 0, stream>>>(h2b, offsets, csr_pk,
                                               dinv, b2, outp, nullptr, 1, n);
}

// Round 13
// 301.746 us; speedup vs baseline: 1.1185x; 1.0501x over previous
//
#include <hip/hip_runtime.h>

// ---------------------------------------------------------------------------
// GCN 2-layer forward on MI355X.
// out = relu(Ahat * relu((Ahat*X)*W1 + b1) * W2 + b2),  Ahat = D^-1/2 (A+I) D^-1/2
// R3: GEMMs = bf16-split MFMA (Ootomo 3-mult). R9: record-based agg.
// R11: XCD-partitioned CSR fill (coalesced scatter lines).
// R12: GEMM retile 128x128 -> 32x128. R11 profile: MfmaUtil 7%, Occupancy 17%,
//     grid 782/391 blocks (1.5-3/CU) = grid starvation; memory floor is
//     ~13us/GEMM but measured 50us. 32x128: 3126/1563 blocks, 25.6KB LDS
//     (6 blocks/CU), acc 16 VGPR/wave -> occupancy ~6x, latency hidden.
// R13 fix: 'short4' typedef collided with HIP's built-in -> renamed bfs4.
// ---------------------------------------------------------------------------

#define C_IN   128
#define C_HID  256
#define C_OUT  128

typedef __attribute__((ext_vector_type(8))) short short8;
typedef __attribute__((ext_vector_type(4))) short bfs4;
typedef __attribute__((ext_vector_type(4))) float floatx4;

__device__ __forceinline__ unsigned short f2bf(float f) {
    unsigned u = __float_as_uint(f);
    u += 0x7FFFu + ((u >> 16) & 1u);      // RNE
    return (unsigned short)(u >> 16);
}
__device__ __forceinline__ float bf2f(unsigned short b) {
    return __uint_as_float(((unsigned)b) << 16);
}
__device__ __forceinline__ unsigned pack_hilo(float f) {
    unsigned short hi = f2bf(f);
    unsigned short lo = f2bf(f - bf2f(hi));
    return ((unsigned)hi << 16) | (unsigned)lo;
}
__device__ __forceinline__ float bflo(unsigned v) {
    return __uint_as_float((v & 0xFFFFu) << 16);
}
__device__ __forceinline__ float bfhi(unsigned v) {
    return __uint_as_float(v & 0xFFFF0000u);
}

// ---------------- degree histogram ----------------
__global__ void deg_kernel(const int* __restrict__ dst, int* __restrict__ counts, int E) {
    int e = blockIdx.x * blockDim.x + threadIdx.x;
    if (e < E) atomicAdd(&counts[dst[e]], 1);
}

// ---------------- multi-block scan: 1024 counts per block ----------------
#define SCHUNK 1024

__global__ __launch_bounds__(256) void scan_reduce(const int* __restrict__ counts,
                                                   int* __restrict__ block_sums, int n) {
    int b = blockIdx.x;
    int base = b * SCHUNK;
    int t = threadIdx.x;
    int s = 0;
    #pragma unroll
    for (int u = 0; u < 4; ++u) {
        int i = base + t * 4 + u;
        if (i < n) s += counts[i];
    }
    #pragma unroll
    for (int off = 32; off; off >>= 1) s += __shfl_down(s, off, 64);
    __shared__ int ws[4];
    int wave = t >> 6;
    if ((t & 63) == 0) ws[wave] = s;
    __syncthreads();
    if (t == 0) block_sums[b] = ws[0] + ws[1] + ws[2] + ws[3];
}

__global__ __launch_bounds__(64) void scan_sums(const int* __restrict__ block_sums,
                                                int* __restrict__ block_base, int nb,
                                                int* __restrict__ offsets, int n, int E) {
    int t = threadIdx.x;
    int v = (t < nb) ? block_sums[t] : 0;
    int x = v;
    #pragma unroll
    for (int off = 1; off < 64; off <<= 1) {
        int y = __shfl_up(x, off, 64);
        if (t >= off) x += y;
    }
    if (t < nb) block_base[t] = x - v;
    if (t == 0) offsets[n] = E;
}

// reads counts (PRESERVED), writes offsets + cursor (separate) + fused dinv.
__global__ __launch_bounds__(256) void scan_apply(const int* __restrict__ counts,
                                                  const int* __restrict__ block_base,
                                                  int* __restrict__ offsets,
                                                  int* __restrict__ cursor,
                                                  float* __restrict__ dinv, int n) {
    int b = blockIdx.x;
    int base_i = b * SCHUNK;
    int t = threadIdx.x;
    int c[4];
    #pragma unroll
    for (int u = 0; u < 4; ++u) {
        int i = base_i + t * 4 + u;
        c[u] = (i < n) ? counts[i] : 0;
    }
    int tot = c[0] + c[1] + c[2] + c[3];
    int x = tot;
    int lane = t & 63;
    #pragma unroll
    for (int off = 1; off < 64; off <<= 1) {
        int y = __shfl_up(x, off, 64);
        if (lane >= off) x += y;
    }
    __shared__ int ws[4];
    int wave = t >> 6;
    if (lane == 63) ws[wave] = x;
    __syncthreads();
    int wbase = 0;
    for (int w = 0; w < wave; ++w) wbase += ws[w];
    int run = block_base[b] + wbase + (x - tot);
    #pragma unroll
    for (int u = 0; u < 4; ++u) {
        int i = base_i + t * 4 + u;
        if (i < n) {
            offsets[i] = run;
            cursor[i]  = run;
            dinv[i]    = rsqrtf((float)(c[u] + 1));   // +1 self-loop
            run += c[u];
        }
    }
}

// ---------------- XCD-partitioned CSR fill (R11) ----------------
__global__ __launch_bounds__(256) void fill_csr_part(
        const int* __restrict__ src, const int* __restrict__ dst,
        const int* __restrict__ counts, int* __restrict__ cursor,
        unsigned* __restrict__ csr_pk, int E, int n) {
    int group = blockIdx.x & 7;
    int sub   = blockIdx.x >> 3;
    int nblk  = gridDim.x >> 3;            // blocks per group
    int chunk = (n + 7) / 8;
    int nlo = group * chunk;
    int nhi = min(n, nlo + chunk);
    int stride = nblk * 256;
    for (int e = sub * 256 + threadIdx.x; e < E; e += stride) {
        int d = dst[e];
        if (d >= nlo && d < nhi) {
            int s = src[e];
            unsigned rec = (unsigned)s | ((unsigned)counts[s] << 17);
            int p = atomicAdd(&cursor[d], 1);
            csr_pk[p] = rec;
        }
    }
}

// ---------------- weight cast+transpose: W[K][N] f32 -> Wt[N][K] packed ----
__global__ void cast_w_t(const float* __restrict__ W, unsigned* __restrict__ Wtp,
                         int K, int N) {
    int idx = blockIdx.x * blockDim.x + threadIdx.x;
    if (idx < K * N) {
        int k = idx / N, nn = idx - k * N;
        Wtp[(size_t)nn * K + k] = pack_hilo(W[idx]);
    }
}

// ---------------- x -> bf16 cast, 4 elems/thread ----------------
__global__ void cast_x_bf16(const float* __restrict__ x, unsigned* __restrict__ xb2,
                            int count4) {
    int idx = blockIdx.x * blockDim.x + threadIdx.x;
    if (idx < count4) {
        float4 f = ((const float4*)x)[idx];
        unsigned lo = (unsigned)f2bf(f.x) | ((unsigned)f2bf(f.y) << 16);
        unsigned hi = (unsigned)f2bf(f.z) | ((unsigned)f2bf(f.w) << 16);
        ((uint2*)xb2)[idx] = make_uint2(lo, hi);
    }
}

// ---------------- pull aggregation: wave/node, packed records ---------------
__global__ __launch_bounds__(256) void agg_kernel(
        const unsigned short* __restrict__ hb, const int* __restrict__ offsets,
        const unsigned* __restrict__ csr_pk, const float* __restrict__ dinv,
        const float* __restrict__ bias, float* __restrict__ out_f,
        unsigned* __restrict__ out_p, int relu_flag, int n) {
    int node = blockIdx.x * 4 + (threadIdx.x >> 6);
    if (node >= n) return;
    int lane = threadIdx.x & 63;

    const unsigned* hrow = (const unsigned*)hb;   // row j = 64 uints
    float di = dinv[node];
    unsigned sv = hrow[(size_t)node * 64 + lane];
    float a0 = di * bflo(sv);
    float a1 = di * bfhi(sv);

    int lo = offsets[node], hi = offsets[node + 1];

    unsigned rec[8];
    #pragma unroll
    for (int u = 0; u < 8; ++u)
        rec[u] = __builtin_nontemporal_load(&csr_pk[lo + u]);   // slack covers deg==0

    for (int k = lo; k < hi; k += 8) {
        int jj[8]; float w[8];
        #pragma unroll
        for (int u = 0; u < 8; ++u) {
            bool ok = (k + u) < hi;
            jj[u] = ok ? (int)(rec[u] & 0x1FFFFu) : 0;
            w[u]  = ok ? rsqrtf((float)((rec[u] >> 17) + 1u)) : 0.0f;
        }
        unsigned v[8];
        #pragma unroll
        for (int u = 0; u < 8; ++u)
            v[u] = hrow[(size_t)jj[u] * 64 + lane];
        #pragma unroll
        for (int u = 0; u < 8; ++u)                             // prefetch next batch
            rec[u] = __builtin_nontemporal_load(&csr_pk[k + 8 + u]);
        #pragma unroll
        for (int u = 0; u < 8; ++u) {
            a0 += w[u] * bflo(v[u]);
            a1 += w[u] * bfhi(v[u]);
        }
    }

    int c0 = lane * 2;
    float v0 = di * a0, v1f = di * a1;
    if (bias) { v0 += bias[c0]; v1f += bias[c0 + 1]; }
    if (relu_flag) { v0 = fmaxf(v0, 0.0f); v1f = fmaxf(v1f, 0.0f); }
    if (out_f) {
        unsigned long long ov = ((unsigned long long)__float_as_uint(v1f) << 32)
                              | (unsigned long long)__float_as_uint(v0);
        __builtin_nontemporal_store(ov, (unsigned long long*)(out_f + (size_t)node * 128 + c0));
    } else {
        unsigned long long ov = ((unsigned long long)pack_hilo(v1f) << 32)
                              | (unsigned long long)pack_hilo(v0);
        __builtin_nontemporal_store(ov, (unsigned long long*)(out_p + (size_t)node * 128 + c0));
    }
}

// ---------------- bf16-split MFMA GEMM, 32x128 tile (R12) ------------------
// C = A*B (+bias)(relu). A: [M][K] packed hi|lo. Btp: [N][K] packed (B^T).
// 4 waves; wave wv covers all 32 rows x 32 cols at n0w=wv*32: 2x2 frags of
// 16x16x32, 3 mults each = 12 MFMA/kstep. LDS 25.6KB -> 6 blocks/CU.
// Output: Cf (f32) | Cp (packed) | Cb (bf16).
#define TM 32
#define TN 128
#define TK 32
#define LDK 40    // halfs per LDS row: 80B stride -> b128 frag reads 2-way (free)

__global__ __launch_bounds__(256) void mfma_gemm(
        const unsigned* __restrict__ Ap, const unsigned* __restrict__ Btp,
        const float* __restrict__ bias, float* __restrict__ Cf,
        unsigned* __restrict__ Cp, unsigned short* __restrict__ Cb,
        int M, int K, int N, int relu_flag) {
    __shared__ unsigned short smem[320 * LDK];       // 25.6 KB
    unsigned short* As_hi = smem;                    // 32 rows
    unsigned short* As_lo = smem + 32 * LDK;         // 32 rows
    unsigned short* Bs_hi = smem + 64 * LDK;         // 128 rows
    unsigned short* Bs_lo = smem + 192 * LDK;        // 128 rows

    int tid = threadIdx.x;
    int lane = tid & 63;
    int wv = tid >> 6;
    int n0w = wv * 32;
    int row0 = blockIdx.x * TM;
    int col0 = blockIdx.y * TN;

    // A staging: 32 rows x 32 uints; thread: row=tid>>3, 4 uints at (tid&7)*4
    int a_r  = tid >> 3;           // 0..31
    int a_kc = (tid & 7) * 4;      // 0,4,..,28
    // B staging: 128 rows x 32 uints via p-loop; thread: row=(tid>>2)+p*64,
    // 8 uints at (tid&3)*8
    int b_r  = tid >> 2;           // 0..63
    int b_kc = (tid & 3) * 8;

    floatx4 acc[2][2];
    #pragma unroll
    for (int i = 0; i < 2; ++i)
        #pragma unroll
        for (int j = 0; j < 2; ++j)
            acc[i][j] = (floatx4){0.f, 0.f, 0.f, 0.f};

    for (int k0 = 0; k0 < K; k0 += TK) {
        int ar = row0 + a_r;
        uint4 av = (ar < M) ? *(const uint4*)(Ap + (size_t)ar * K + k0 + a_kc)
                            : make_uint4(0, 0, 0, 0);
        uint4 bv[2][2];
        #pragma unroll
        for (int p = 0; p < 2; ++p) {
            const uint4* pb = (const uint4*)(Btp + (size_t)(col0 + b_r + p * 64) * K + k0 + b_kc);
            bv[p][0] = pb[0];  bv[p][1] = pb[1];
        }
        __syncthreads();          // prev iter frag reads done
        {   // A unpack: 4 uints -> bfs4 hi/lo
            unsigned ua[4] = {av.x, av.y, av.z, av.w};
            bfs4 ah4, al4;
            #pragma unroll
            for (int j = 0; j < 4; ++j) {
                ah4[j] = (short)(ua[j] >> 16);  al4[j] = (short)(ua[j] & 0xFFFFu);
            }
            *(bfs4*)&As_hi[a_r * LDK + a_kc] = ah4;
            *(bfs4*)&As_lo[a_r * LDK + a_kc] = al4;
        }
        #pragma unroll
        for (int p = 0; p < 2; ++p) {
            int r = b_r + p * 64;
            unsigned ub[8] = {bv[p][0].x, bv[p][0].y, bv[p][0].z, bv[p][0].w,
                              bv[p][1].x, bv[p][1].y, bv[p][1].z, bv[p][1].w};
            short8 bhs, bls;
            #pragma unroll
            for (int j = 0; j < 8; ++j) {
                bhs[j] = (short)(ub[j] >> 16);  bls[j] = (short)(ub[j] & 0xFFFFu);
            }
            *(short8*)&Bs_hi[r * LDK + b_kc] = bhs;
            *(short8*)&Bs_lo[r * LDK + b_kc] = bls;
        }
        __syncthreads();
        short8 ah[2], al[2], bh[2], bl[2];
        int ka = (lane >> 4) * 8;
        #pragma unroll
        for (int mi = 0; mi < 2; ++mi) {
            int rr = mi * 16 + (lane & 15);
            ah[mi] = *(const short8*)&As_hi[rr * LDK + ka];
            al[mi] = *(const short8*)&As_lo[rr * LDK + ka];
        }
        #pragma unroll
        for (int ni = 0; ni < 2; ++ni) {
            int cc = n0w + ni * 16 + (lane & 15);
            bh[ni] = *(const short8*)&Bs_hi[cc * LDK + ka];
            bl[ni] = *(const short8*)&Bs_lo[cc * LDK + ka];
        }
        #pragma unroll
        for (int mi = 0; mi < 2; ++mi)
            #pragma unroll
            for (int ni = 0; ni < 2; ++ni) {
                acc[mi][ni] = __builtin_amdgcn_mfma_f32_16x16x32_bf16(al[mi], bh[ni], acc[mi][ni], 0, 0, 0);
                acc[mi][ni] = __builtin_amdgcn_mfma_f32_16x16x32_bf16(ah[mi], bl[ni], acc[mi][ni], 0, 0, 0);
                acc[mi][ni] = __builtin_amdgcn_mfma_f32_16x16x32_bf16(ah[mi], bh[ni], acc[mi][ni], 0, 0, 0);
            }
    }

    // epilogue: C/D mapping col=lane&15, row=(lane>>4)*4+reg
    #pragma unroll
    for (int mi = 0; mi < 2; ++mi) {
        #pragma unroll
        for (int reg = 0; reg < 4; ++reg) {
            int r = row0 + mi * 16 + (lane >> 4) * 4 + reg;
            if (r < M) {
                #pragma unroll
                for (int ni = 0; ni < 2; ++ni) {
                    int c = col0 + n0w + ni * 16 + (lane & 15);
                    float v = acc[mi][ni][reg];
                    if (bias) v += bias[c];
                    if (relu_flag) v = fmaxf(v, 0.0f);
                    if (Cf)      Cf[(size_t)r * N + c] = v;
                    else if (Cp) Cp[(size_t)r * N + c] = pack_hilo(v);
                    else         Cb[(size_t)r * N + c] = f2bf(v);
                }
            }
        }
    }
}

// ---------------------------------------------------------------------------
extern "C" void kernel_launch(void* const* d_in, const int* in_sizes, int n_in,
                              void* d_out, int out_size, void* d_ws, size_t ws_size,
                              hipStream_t stream) {
    const float* x  = (const float*)d_in[0];
    const int*   ei = (const int*)d_in[1];
    const float* W1 = (const float*)d_in[2];
    const float* b1 = (const float*)d_in[3];
    const float* W2 = (const float*)d_in[4];
    const float* b2 = (const float*)d_in[5];

    const int n = in_sizes[0] / C_IN;          // 50000
    const int E = in_sizes[1] / 2;             // 800000

    const int* src = ei;
    const int* dst = ei + E;

    // workspace layout (~81 MB)
    unsigned short* h2b = (unsigned short*)d_ws;         // n*128 bf16
    unsigned* z1p = (unsigned*)(h2b + (size_t)n * C_OUT);// n*256 packed
    unsigned short* xb = (unsigned short*)(z1p + (size_t)n * C_HID); // n*128 bf16
    unsigned* w1t = (unsigned*)(xb + (size_t)n * C_IN);  // 128*256
    unsigned* w2t = w1t + C_IN * C_HID;                  // 256*128
    float*    dinv = (float*)(w2t + C_HID * C_OUT);      // n
    int* counts  = (int*)(dinv + n);                     // n (preserved)
    int* cursor  = counts + n;                           // n (separate)
    int* offsets = cursor + n;                           // n+1
    unsigned* csr_pk = (unsigned*)(offsets + n + 1);     // E uint (+64 slack)
    int* block_sums = (int*)(csr_pk + E + 64);           // 64
    int* block_base = block_sums + 64;                   // 64

    unsigned* agg0p = (unsigned*)d_out;    // n*128 packed, overwritten by final out
    float*    outp  = (float*)d_out;

    const int nb = (n + SCHUNK - 1) / SCHUNK;            // 49

    // ---- CSR build ----
    hipMemsetAsync(counts, 0, (size_t)n * sizeof(int), stream);
    deg_kernel<<<(E + 255) / 256, 256, 0, stream>>>(dst, counts, E);
    scan_reduce<<<nb, 256, 0, stream>>>(counts, block_sums, n);
    scan_sums<<<1, 64, 0, stream>>>(block_sums, block_base, nb, offsets, n, E);
    scan_apply<<<nb, 256, 0, stream>>>(counts, block_base, offsets, cursor, dinv, n);
    fill_csr_part<<<8 * 391, 256, 0, stream>>>(src, dst, counts, cursor, csr_pk, E, n);

    // ---- casts (tiny) ----
    cast_w_t<<<(C_IN * C_HID + 255) / 256, 256, 0, stream>>>(W1, w1t, C_IN, C_HID);
    cast_w_t<<<(C_HID * C_OUT + 255) / 256, 256, 0, stream>>>(W2, w2t, C_HID, C_OUT);
    {
        int count4 = n * C_IN / 4;
        cast_x_bf16<<<(count4 + 255) / 256, 256, 0, stream>>>(x, (unsigned*)xb, count4);
    }

    const int agg_blocks = (n + 3) / 4;

    // ---- layer 1: agg0 = Ahat*X (packed) ; z1 = relu(agg0@W1 + b1) (packed) ----
    agg_kernel<<<agg_blocks, 256, 0, stream>>>(xb, offsets, csr_pk,
                                               dinv, nullptr, nullptr, agg0p, 0, n);
    {
        dim3 grid((n + TM - 1) / TM, C_HID / TN);        // (1563, 2)
        mfma_gemm<<<grid, 256, 0, stream>>>(agg0p, w1t, b1, nullptr, z1p, nullptr,
                                            n, C_IN, C_HID, 1);
    }

    // ---- layer 2: h2 = z1@W2 (bf16) ; out = relu(Ahat*h2 + b2) ----
    {
        dim3 grid((n + TM - 1) / TM, C_OUT / TN);        // (1563, 1)
        mfma_gemm<<<grid, 256, 0, stream>>>(z1p, w2t, nullptr, nullptr, nullptr, h2b,
                                            n, C_HID, C_OUT, 0);
    }
    agg_kernel<<<agg_blocks, 256, 0, stream>>>(h2b, offsets, csr_pk,
                                               dinv, b2, outp, nullptr, 1, n);
}